// Round 1
// baseline (959.634 us; speedup 1.0000x reference)
//
#include <hip/hip_runtime.h>
#include <stdint.h>

// HungarianMatcher on MI355X.
// Pipeline (all on `stream`, graph-capture safe):
//   1) pack_kernel:  nearest-downsample target_masks [8,32,512,512] -> bitmask [8,65536] u32
//   2) count_kernel: per-(b,t) popcount -> tm_sums [8,32]  (dice denominator)
//   3) main_kernel:  per-(b,n) block: softplus/sigmoid sums + 32 binary-weighted dots
//                    + class softmax -> cost[8,100,32] (fp32)
//   4) hungarian_kernel: exact JV shortest-augmenting-path (fp64, LDS) per batch,
//                    emits src/tgt index pairs as int32.

#define BATCH 8
#define NQ    100
#define NT    32
#define HWP   65536      // 256*256
#define NCLS  81
#define BIGV  1.0e6

// -------------------------------------------------------------------------
// 1) Pack target masks (nearest 2x downsample) into per-pixel 32-bit masks.
__global__ __launch_bounds__(256) void pack_kernel(const float* __restrict__ tmask,
                                                   uint32_t* __restrict__ packed) {
    int idx = blockIdx.x * 256 + threadIdx.x;   // [0, BATCH*HWP)
    int b = idx >> 16;
    int p = idx & 65535;
    int y = p >> 8, x = p & 255;
    const float* base = tmask + (size_t)b * NT * 262144 + (size_t)(2 * y) * 512 + (2 * x);
    uint32_t w = 0;
#pragma unroll
    for (int t = 0; t < NT; ++t) {
        float v = base[(size_t)t * 262144];
        w |= (v > 0.5f ? 1u : 0u) << t;
    }
    packed[idx] = w;
}

// -------------------------------------------------------------------------
// 2) Per-(b,t) counts of set bits -> tm_sums (float).
__global__ __launch_bounds__(256) void count_kernel(const uint32_t* __restrict__ packed,
                                                    float* __restrict__ tm_sums) {
    int b = blockIdx.x;
    int tid = threadIdx.x;
    __shared__ int cnt[NT];
    if (tid < NT) cnt[tid] = 0;
    __syncthreads();
    const uint32_t* pb = packed + (size_t)b * HWP;
    int local[NT];
#pragma unroll
    for (int t = 0; t < NT; ++t) local[t] = 0;
    for (int it = 0; it < HWP / 256; ++it) {
        uint32_t w = pb[it * 256 + tid];
#pragma unroll
        for (int t = 0; t < NT; ++t) local[t] += (int)((w >> t) & 1u);
    }
#pragma unroll
    for (int t = 0; t < NT; ++t) atomicAdd(&cnt[t], local[t]);
    __syncthreads();
    if (tid < NT) tm_sums[b * NT + tid] = (float)cnt[tid];
}

// -------------------------------------------------------------------------
// 3) Main fused cost kernel: one block per (n, b).
__global__ __launch_bounds__(256) void main_kernel(const float* __restrict__ logits,
                                                   const float* __restrict__ pmask,
                                                   const int* __restrict__ labels,
                                                   const uint32_t* __restrict__ packed,
                                                   const float* __restrict__ tm_sums,
                                                   float* __restrict__ costm) {
    const int n = blockIdx.x;
    const int b = blockIdx.y;
    const int tid = threadIdx.x;

    const float4* pm4 = (const float4*)(pmask + ((size_t)(b * NQ + n)) * HWP);
    const uint4*  pk4 = (const uint4*)(packed + (size_t)b * HWP);

    float acc_pm[NT], acc_sig[NT];
#pragma unroll
    for (int t = 0; t < NT; ++t) { acc_pm[t] = 0.f; acc_sig[t] = 0.f; }
    float s_sp = 0.f, s_sig = 0.f;

    for (int it = 0; it < HWP / 4 / 256; ++it) {     // 64 iterations
        float4 v = pm4[it * 256 + tid];
        uint4  w = pk4[it * 256 + tid];
#pragma unroll
        for (int e = 0; e < 4; ++e) {
            float pv = (&v.x)[e];
            uint32_t wb = (&w.x)[e];
            float ax = fabsf(pv);
            float en = __expf(-ax);                  // exp(-|x|), never overflows
            float inv = 1.0f / (1.0f + en);
            float sig = (pv >= 0.f) ? inv : en * inv;            // sigmoid(pv)
            float sp  = fmaxf(pv, 0.f) + __logf(1.0f + en);      // softplus(pv)
            s_sp += sp;
            s_sig += sig;
#pragma unroll
            for (int t = 0; t < NT; ++t) {
                float bt = (float)((wb >> t) & 1u);
                acc_pm[t]  = fmaf(pv,  bt, acc_pm[t]);
                acc_sig[t] = fmaf(sig, bt, acc_sig[t]);
            }
        }
    }

    // ---- cross-thread reduction: wave shuffles, then 4 partials in LDS ----
    __shared__ float red[4][NT * 2 + 2];
    const int lane = tid & 63;
    const int wv = tid >> 6;
#pragma unroll
    for (int t = 0; t < NT; ++t) {
        float a = acc_pm[t];
#pragma unroll
        for (int s = 32; s > 0; s >>= 1) a += __shfl_down(a, s, 64);
        if (lane == 0) red[wv][t] = a;
        float c = acc_sig[t];
#pragma unroll
        for (int s = 32; s > 0; s >>= 1) c += __shfl_down(c, s, 64);
        if (lane == 0) red[wv][NT + t] = c;
    }
    {
        float a = s_sp;
#pragma unroll
        for (int s = 32; s > 0; s >>= 1) a += __shfl_down(a, s, 64);
        if (lane == 0) red[wv][2 * NT] = a;
        float c = s_sig;
#pragma unroll
        for (int s = 32; s > 0; s >>= 1) c += __shfl_down(c, s, 64);
        if (lane == 0) red[wv][2 * NT + 1] = c;
    }
    __shared__ float sh_mx, sh_sum;
    __syncthreads();
    if (tid == 0) {     // class softmax denominator over all 81 classes
        const float* lg = logits + (size_t)(b * NQ + n) * NCLS;
        float mx = -1e30f;
        for (int c = 0; c < NCLS; ++c) mx = fmaxf(mx, lg[c]);
        float s = 0.f;
        for (int c = 0; c < NCLS; ++c) s += __expf(lg[c] - mx);
        sh_mx = mx; sh_sum = s;
    }
    __syncthreads();
    if (tid < NT) {
        int t = tid;
        float dot_pm  = red[0][t] + red[1][t] + red[2][t] + red[3][t];
        float dot_sig = red[0][NT + t] + red[1][NT + t] + red[2][NT + t] + red[3][NT + t];
        float ssp = red[0][2*NT] + red[1][2*NT] + red[2][2*NT] + red[3][2*NT];
        float ssg = red[0][2*NT+1] + red[1][2*NT+1] + red[2][2*NT+1] + red[3][2*NT+1];
        const float* lg = logits + (size_t)(b * NQ + n) * NCLS;
        int lbl = labels[b * NT + t];                 // in [0,80): last class never selected
        float prob = __expf(lg[lbl] - sh_mx) / sh_sum;
        float c_class = -prob;
        float c_mask = (ssp - dot_pm) * (1.0f / (float)HWP);
        float c_dice = 1.0f - (2.0f * dot_sig + 1.0f) / (ssg + tm_sums[b * NT + t] + 1.0f);
        float c = c_class + c_mask + c_dice;
        if (isnan(c)) c = (float)BIGV;
        else if (isinf(c)) c = (c > 0.f) ? (float)BIGV : -(float)BIGV;
        costm[((size_t)(b * NQ + n)) * NT + t] = c;
    }
}

// -------------------------------------------------------------------------
// 4) Exact Jonker-Volgenant Hungarian per batch (fp64, transposed 32x100).
//    One block of 128 threads per batch; mirrors the numpy reference exactly,
//    including first-min tie-break in the argmin.
__global__ __launch_bounds__(128) void hungarian_kernel(const float* __restrict__ costm,
                                                        int* __restrict__ out) {
    const int b = blockIdx.x;
    const int tid = threadIdx.x;
    const int n = NT, m = NQ;

    __shared__ double Ct[NT][NQ];          // transposed cost: Ct[target][query]
    __shared__ double u[NT + 1], v[NQ + 1], minv[NQ + 1];
    __shared__ int p[NQ + 1], way[NQ + 1];
    __shared__ unsigned char used[NQ + 1];
    __shared__ double red_v[128];
    __shared__ int red_j[128];
    __shared__ int sh_j0;
    __shared__ double sh_delta;

    for (int idx = tid; idx < n * m; idx += 128) {
        int i = idx / m, j = idx % m;
        Ct[i][j] = (double)costm[((size_t)b * NQ + j) * NT + i];
    }
    for (int j = tid; j <= m; j += 128) { v[j] = 0.0; p[j] = 0; way[j] = 0; }
    if (tid <= n) u[tid] = 0.0;
    __syncthreads();

    for (int i = 1; i <= n; ++i) {
        if (tid == 0) { p[0] = i; sh_j0 = 0; }
        for (int j = tid; j <= m; j += 128) { minv[j] = 1e300; used[j] = 0; }
        __syncthreads();
        while (true) {
            int j0 = sh_j0;
            if (tid == 0) used[j0] = 1;
            __syncthreads();
            int i0 = p[j0];
            double u_i0 = u[i0];
            double best = 1e300; int bestj = m + 1;
            int j = tid + 1;                       // 128 threads cover j=1..100
            if (j <= m && !used[j]) {
                double cur = Ct[i0 - 1][j - 1] - u_i0 - v[j];
                if (cur < minv[j]) { minv[j] = cur; way[j] = j0; }
                double mv = minv[j];
                best = mv; bestj = j;
            }
            red_v[tid] = best; red_j[tid] = bestj;
            __syncthreads();
            for (int s = 64; s > 0; s >>= 1) {
                if (tid < s) {
                    double ov = red_v[tid + s]; int oj = red_j[tid + s];
                    if (ov < red_v[tid] || (ov == red_v[tid] && oj < red_j[tid])) {
                        red_v[tid] = ov; red_j[tid] = oj;
                    }
                }
                __syncthreads();
            }
            if (tid == 0) { sh_delta = red_v[0]; sh_j0 = red_j[0]; }
            __syncthreads();
            double delta = sh_delta;
            int j1 = sh_j0;
            for (int jj = tid; jj <= m; jj += 128) {
                if (used[jj]) { u[p[jj]] += delta; v[jj] -= delta; }  // p[] distinct over used
                else if (jj >= 1) minv[jj] -= delta;
            }
            __syncthreads();
            if (p[j1] == 0) break;                 // uniform branch (LDS read)
        }
        if (tid == 0) {                            // augment along `way`
            int j0 = sh_j0;
            while (j0 != 0) { int j1 = way[j0]; p[j0] = p[j1]; j0 = j1; }
        }
        __syncthreads();
    }

    if (tid == 0) {
        // queries ascending == argsort(rows); 32 matched pairs.
        int k = 0;
        for (int j = 1; j <= m; ++j) {
            if (p[j] != 0) {
                out[b * NT + k] = j - 1;                   // src: query index
                out[BATCH * NT + b * NT + k] = p[j] - 1;   // tgt: target index
                ++k;
            }
        }
    }
}

// -------------------------------------------------------------------------
extern "C" void kernel_launch(void* const* d_in, const int* in_sizes, int n_in,
                              void* d_out, int out_size, void* d_ws, size_t ws_size,
                              hipStream_t stream) {
    const float* logits = (const float*)d_in[0];   // [8,100,81]
    const float* pmasks = (const float*)d_in[1];   // [8,100,256,256]
    const float* tmasks = (const float*)d_in[2];   // [8,32,512,512]
    const int*   labels = (const int*)d_in[3];     // [8,32]

    uint8_t* ws = (uint8_t*)d_ws;
    uint32_t* packed = (uint32_t*)ws;                                   // 2 MiB
    float* tm_sums = (float*)(ws + (size_t)BATCH * HWP * 4);            // 1 KiB
    float* costm   = (float*)(ws + (size_t)BATCH * HWP * 4 + 4096);     // 100 KiB

    int* out = (int*)d_out;    // int32 indices: src [8,32] then tgt [8,32]

    pack_kernel<<<BATCH * HWP / 256, 256, 0, stream>>>(tmasks, packed);
    count_kernel<<<BATCH, 256, 0, stream>>>(packed, tm_sums);
    main_kernel<<<dim3(NQ, BATCH), 256, 0, stream>>>(logits, pmasks, labels, packed, tm_sums, costm);
    hungarian_kernel<<<BATCH, 128, 0, stream>>>(costm, out);
}

// Round 2
// 830.991 us; speedup vs baseline: 1.1548x; 1.1548x over previous
//
#include <hip/hip_runtime.h>
#include <stdint.h>

// HungarianMatcher on MI355X — round 2.
// 1) pack_kernel: nearest-2x downsample target_masks -> per-pixel u32 bitmask,
//    fused per-(b,t) popcount via wave ballots + atomicAdd (count_kernel removed).
// 2) main_kernel: 256 thr = 2 groups x 128; each group owns 16 targets ->
//    16+16 accumulator VGPRs (no spill, unlike round 1's 64-acc spill at VGPR=52).
// 3) hungarian_kernel: exact JV, ONE wave per batch, col state in lane-owned
//    registers, cross-lane via shuffles, u[] in LDS with deferred updates.
//    Zero barriers inside the Dijkstra loop; exact fp64 + first-min tie-break.

#define BATCH 8
#define NQ    100
#define NT    32
#define HWP   65536      // 256*256
#define NCLS  81
#define BIGV  1.0e6

// -------------------------------------------------------------------------
// 1) Pack + count.
__global__ __launch_bounds__(256) void pack_kernel(const float* __restrict__ tmask,
                                                   uint32_t* __restrict__ packed,
                                                   int* __restrict__ tm_counts) {
    int idx = blockIdx.x * 256 + threadIdx.x;   // [0, BATCH*HWP)
    int b = idx >> 16;
    int p = idx & 65535;
    int y = p >> 8, x = p & 255;
    const float* base = tmask + (size_t)b * NT * 262144 + (size_t)(2 * y) * 512 + (2 * x);
    uint32_t w = 0;
#pragma unroll
    for (int t = 0; t < NT; ++t) {
        float v = base[(size_t)t * 262144];
        w |= (v > 0.5f ? 1u : 0u) << t;
    }
    packed[idx] = w;

    // fused per-(b,t) popcount: one ballot per target, one atomic per wave.
    int lane = threadIdx.x & 63;
    int mycnt = 0;
#pragma unroll
    for (int t = 0; t < NT; ++t) {
        unsigned long long m = __ballot((w >> t) & 1u);
        if (lane == t) mycnt = __popcll(m);
    }
    if (lane < NT) atomicAdd(&tm_counts[b * NT + lane], mycnt);
}

// -------------------------------------------------------------------------
// 2) Main fused cost kernel: one block per (n, b); 2 groups x 128 threads,
//    group g handles targets [g*16, g*16+16).
__global__ __launch_bounds__(256) void main_kernel(const float* __restrict__ logits,
                                                   const float* __restrict__ pmask,
                                                   const int* __restrict__ labels,
                                                   const uint32_t* __restrict__ packed,
                                                   const int* __restrict__ tm_counts,
                                                   float* __restrict__ costm) {
    const int n = blockIdx.x;
    const int b = blockIdx.y;
    const int tid = threadIdx.x;
    const int g = tid >> 7;          // group 0/1
    const int k = tid & 127;         // lane-in-group
    const int shift = g * 16;

    const float4* pm4 = (const float4*)(pmask + ((size_t)(b * NQ + n)) * HWP);
    const uint4*  pk4 = (const uint4*)(packed + (size_t)b * HWP);

    float acc_pm[16], acc_sig[16];
#pragma unroll
    for (int t = 0; t < 16; ++t) { acc_pm[t] = 0.f; acc_sig[t] = 0.f; }
    float s_sp = 0.f, s_sig = 0.f;

    for (int it = 0; it < HWP / 4 / 128; ++it) {     // 128 iterations
        float4 v = pm4[it * 128 + k];
        uint4  w = pk4[it * 128 + k];
#pragma unroll
        for (int e = 0; e < 4; ++e) {
            float pv = (&v.x)[e];
            uint32_t wb = (&w.x)[e] >> shift;        // this group's 16 bits
            float ax = fabsf(pv);
            float en = __expf(-ax);                  // exp(-|x|), never overflows
            float inv = __builtin_amdgcn_rcpf(1.0f + en);
            float sig = (pv >= 0.f) ? inv : en * inv;            // sigmoid(pv)
            float sp  = fmaxf(pv, 0.f) + __logf(1.0f + en);      // softplus(pv)
            s_sp += sp;
            s_sig += sig;
#pragma unroll
            for (int t = 0; t < 16; ++t) {
                float bt = (float)((wb >> t) & 1u);
                acc_pm[t]  = fmaf(pv,  bt, acc_pm[t]);
                acc_sig[t] = fmaf(sig, bt, acc_sig[t]);
            }
        }
    }

    // ---- cross-thread reduction: wave shuffles, then per-wave partials ----
    __shared__ float red[4][34];     // [wave][16 pm | 16 sig | ssp | ssig]
    const int lane = tid & 63;
    const int wv = tid >> 6;         // waves 0,1 = group 0; 2,3 = group 1
#pragma unroll
    for (int t = 0; t < 16; ++t) {
        float a = acc_pm[t];
#pragma unroll
        for (int s = 32; s > 0; s >>= 1) a += __shfl_down(a, s, 64);
        if (lane == 0) red[wv][t] = a;
        float c = acc_sig[t];
#pragma unroll
        for (int s = 32; s > 0; s >>= 1) c += __shfl_down(c, s, 64);
        if (lane == 0) red[wv][16 + t] = c;
    }
    {
        float a = s_sp;
#pragma unroll
        for (int s = 32; s > 0; s >>= 1) a += __shfl_down(a, s, 64);
        if (lane == 0) red[wv][32] = a;
        float c = s_sig;
#pragma unroll
        for (int s = 32; s > 0; s >>= 1) c += __shfl_down(c, s, 64);
        if (lane == 0) red[wv][33] = c;
    }
    __shared__ float sh_mx, sh_sum;
    __syncthreads();
    if (tid == 0) {     // class softmax denominator over all 81 classes
        const float* lg = logits + (size_t)(b * NQ + n) * NCLS;
        float mx = -1e30f;
        for (int c = 0; c < NCLS; ++c) mx = fmaxf(mx, lg[c]);
        float s = 0.f;
        for (int c = 0; c < NCLS; ++c) s += __expf(lg[c] - mx);
        sh_mx = mx; sh_sum = s;
    }
    __syncthreads();
    if (tid < NT) {
        int t = tid;
        int tg = t >> 4;             // which group computed this target
        int tl = t & 15;
        float dot_pm  = red[2 * tg][tl]      + red[2 * tg + 1][tl];
        float dot_sig = red[2 * tg][16 + tl] + red[2 * tg + 1][16 + tl];
        float ssp = red[0][32] + red[1][32];   // group 0 covers all pixels
        float ssg = red[0][33] + red[1][33];
        const float* lg = logits + (size_t)(b * NQ + n) * NCLS;
        int lbl = labels[b * NT + t];          // in [0,80): last class never selected
        float prob = __expf(lg[lbl] - sh_mx) / sh_sum;
        float c_class = -prob;
        float c_mask = (ssp - dot_pm) * (1.0f / (float)HWP);
        float c_dice = 1.0f - (2.0f * dot_sig + 1.0f)
                             / (ssg + (float)tm_counts[b * NT + t] + 1.0f);
        float c = c_class + c_mask + c_dice;
        if (isnan(c)) c = (float)BIGV;
        else if (isinf(c)) c = (c > 0.f) ? (float)BIGV : -(float)BIGV;
        costm[((size_t)(b * NQ + n)) * NT + t] = c;
    }
}

// -------------------------------------------------------------------------
// 3) Exact Jonker-Volgenant Hungarian, one 64-lane wave per batch.
//    Transposed problem: rows = 32 targets, cols = 100 queries.
//    Lane L owns col c0 = L+1 and (if L<36) col c1 = L+65 (1-based).
//    Per-col state (v, minv, way, used, p) lives in lane registers.
//    u[] lives in LDS; updates are deferred to row end (never read same-row).
__global__ __launch_bounds__(64) void hungarian_kernel(const float* __restrict__ costm,
                                                       int* __restrict__ out) {
    const int b = blockIdx.x;
    const int lane = threadIdx.x;

    __shared__ double Ct[NT][NQ];    // Ct[target][query], read-only after init
    __shared__ double u[NT + 1];

    for (int idx = lane; idx < NT * NQ; idx += 64) {
        int t = idx / NQ, q = idx % NQ;
        Ct[t][q] = (double)costm[((size_t)b * NQ + q) * NT + t];
    }
    if (lane <= NT) u[lane] = 0.0;
    __syncthreads();

    const int c0 = lane + 1;
    const bool valid1 = (lane < NQ - 64);          // lanes 0..35
    const int c1 = lane + 65;
    const int cidx1 = valid1 ? (lane + 64) : 0;    // clamped LDS col index

    double v0 = 0.0, v1 = 0.0;
    int p0 = 0, p1 = 0;                            // matched row (0 = free)

    for (int i = 1; i <= NT; ++i) {
        double minv0 = 1e300, minv1 = 1e300;
        int way0 = 0, way1 = 0;
        bool used0 = false, used1 = !valid1;
        double du0 = 0.0, du1 = 0.0, dtot = 0.0;
        int j0 = 0, i0 = i;
        int jfin = 0;

        for (int guard = 0; guard < 160; ++guard) {
            double u_i0 = u[i0];                   // LDS broadcast (wave-uniform addr)
            // relax this row's edges into unused cols
            double cur0 = Ct[i0 - 1][lane] - u_i0 - v0;
            if (!used0 && cur0 < minv0) { minv0 = cur0; way0 = j0; }
            double cur1 = Ct[i0 - 1][cidx1] - u_i0 - v1;
            if (!used1 && cur1 < minv1) { minv1 = cur1; way1 = j0; }
            // per-lane candidate (prefer lower col on ties)
            double bv = 1e301; int bj = 1 << 20;
            if (!used0) { bv = minv0; bj = c0; }
            if (!used1 && minv1 < bv) { bv = minv1; bj = c1; }
            // wave argmin with first-index tie-break
#pragma unroll
            for (int s = 32; s > 0; s >>= 1) {
                double ov = __shfl_down(bv, s, 64);
                int    oj = __shfl_down(bj, s, 64);
                if (ov < bv || (ov == bv && oj < bj)) { bv = ov; bj = oj; }
            }
            double delta = __shfl(bv, 0, 64);
            int j1 = __shfl(bj, 0, 64);
            // apply delta: u[p[used]] deferred via du; v[used]-=; minv[free]-=
            dtot += delta;
            if (used0) { v0 -= delta; du0 += delta; } else { minv0 -= delta; }
            if (valid1) {
                if (used1) { v1 -= delta; du1 += delta; } else { minv1 -= delta; }
            }
            // mark j1 visited (after updates — matches reference order)
            if (c0 == j1) used0 = true;
            if (valid1 && c1 == j1) used1 = true;
            // p[j1]: matched -> continue from its row; free -> done
            int src = (j1 - 1) & 63, slot = (j1 - 1) >> 6;
            int pa = __shfl(p0, src, 64), pb = __shfl(p1, src, 64);
            int pj1 = slot ? pb : pa;
            if (pj1 == 0) { jfin = j1; break; }
            j0 = j1; i0 = pj1;
        }

        // deferred u updates (old matching, before augmentation)
        if (used0 && p0 != 0) u[p0] += du0;
        if (valid1 && used1 && p1 != 0) u[p1] += du1;
        if (lane == 0) u[i] += dtot;

        // augment along `way` (wave-uniform loop via shuffles)
        int jj = jfin;
        for (int guard = 0; guard < 160 && jj != 0; ++guard) {
            int src = (jj - 1) & 63, slot = (jj - 1) >> 6;
            int wa = __shfl(way0, src, 64), wb = __shfl(way1, src, 64);
            int jprev = slot ? wb : wa;
            int pnew;
            if (jprev == 0) pnew = i;
            else {
                int s2 = (jprev - 1) & 63, sl2 = (jprev - 1) >> 6;
                int pa = __shfl(p0, s2, 64), pb = __shfl(p1, s2, 64);
                pnew = sl2 ? pb : pa;
            }
            if (c0 == jj) p0 = pnew;
            if (valid1 && c1 == jj) p1 = pnew;
            jj = jprev;
        }
        __syncthreads();   // make this row's u[] writes visible to next row
    }

    // emit pairs sorted by query index ascending
    unsigned long long m0 = __ballot(p0 != 0);
    unsigned long long m1 = __ballot(valid1 && p1 != 0);
    int base = b * NT;
    if (p0 != 0) {
        int rank = __popcll(m0 & ((1ull << lane) - 1ull));
        out[base + rank] = c0 - 1;
        out[BATCH * NT + base + rank] = p0 - 1;
    }
    if (valid1 && p1 != 0) {
        int rank = __popcll(m0) + __popcll(m1 & ((1ull << lane) - 1ull));
        out[base + rank] = c1 - 1;
        out[BATCH * NT + base + rank] = p1 - 1;
    }
}

// -------------------------------------------------------------------------
extern "C" void kernel_launch(void* const* d_in, const int* in_sizes, int n_in,
                              void* d_out, int out_size, void* d_ws, size_t ws_size,
                              hipStream_t stream) {
    const float* logits = (const float*)d_in[0];   // [8,100,81]
    const float* pmasks = (const float*)d_in[1];   // [8,100,256,256]
    const float* tmasks = (const float*)d_in[2];   // [8,32,512,512]
    const int*   labels = (const int*)d_in[3];     // [8,32]

    uint8_t* ws = (uint8_t*)d_ws;
    uint32_t* packed = (uint32_t*)ws;                                   // 2 MiB
    int* tm_counts = (int*)(ws + (size_t)BATCH * HWP * 4);              // 1 KiB
    float* costm   = (float*)(ws + (size_t)BATCH * HWP * 4 + 4096);     // 100 KiB

    int* out = (int*)d_out;    // int32 indices: src [8,32] then tgt [8,32]

    hipMemsetAsync(tm_counts, 0, BATCH * NT * sizeof(int), stream);
    pack_kernel<<<BATCH * HWP / 256, 256, 0, stream>>>(tmasks, packed, tm_counts);
    main_kernel<<<dim3(NQ, BATCH), 256, 0, stream>>>(logits, pmasks, labels, packed, tm_counts, costm);
    hungarian_kernel<<<BATCH, 64, 0, stream>>>(costm, out);
}

// Round 3
// 605.927 us; speedup vs baseline: 1.5837x; 1.3714x over previous
//
#include <hip/hip_runtime.h>
#include <stdint.h>

// HungarianMatcher on MI355X — round 3: MFMA for the binary-weighted dots.
// 1) pack_kernel: nearest-2x downsample -> per-pixel u32 bitmask + fused counts.
// 2) mfma_kernel: grid (KSPLIT, MTILES, BATCH). Per wave: stage 16x64 A-tiles
//    (pm & sigmoid(pm), fp32->bf16, computed ONCE per pixel — round 2 computed
//    transcendentals twice and was VALU-bound at 253us), unpack B from bits,
//    8x mfma_f32_16x16x32_bf16 per iter, atomicAdd partials to workspace.
// 3) hungarian_kernel: finalize cost matrix (class softmax + mask + dice) in
//    LDS, then exact single-wave JV (unchanged from round 2, absmax 0).

#define BATCH 8
#define NQ    100
#define NT    32
#define HWP   65536      // 256*256
#define NCLS  81
#define BIGV  1.0e6
#define MPAD  112        // 7*16
#define MTILES 7
#define KSPLIT 16
#define KC (HWP / KSPLIT)   // 4096 px per block
#define KW (KC / 4)         // 1024 px per wave
#define NITER (KW / 64)     // 16 k-iters of 64 px

typedef __attribute__((ext_vector_type(8))) short short8;
typedef __attribute__((ext_vector_type(4))) float f32x4;

__device__ inline unsigned short f2bf(float f) {   // RNE fp32->bf16
    uint32_t u = __builtin_bit_cast(uint32_t, f);
    u += 0x7fffu + ((u >> 16) & 1u);
    return (unsigned short)(u >> 16);
}

// -------------------------------------------------------------------------
__global__ __launch_bounds__(256) void pack_kernel(const float* __restrict__ tmask,
                                                   uint32_t* __restrict__ packed,
                                                   int* __restrict__ tm_counts) {
    int idx = blockIdx.x * 256 + threadIdx.x;
    int b = idx >> 16;
    int p = idx & 65535;
    int y = p >> 8, x = p & 255;
    const float* base = tmask + (size_t)b * NT * 262144 + (size_t)(2 * y) * 512 + (2 * x);
    uint32_t w = 0;
#pragma unroll
    for (int t = 0; t < NT; ++t) {
        float v = base[(size_t)t * 262144];
        w |= (v > 0.5f ? 1u : 0u) << t;
    }
    packed[idx] = w;
    int lane = threadIdx.x & 63;
    int mycnt = 0;
#pragma unroll
    for (int t = 0; t < NT; ++t) {
        unsigned long long m = __ballot((w >> t) & 1u);
        if (lane == t) mycnt = __popcll(m);
    }
    if (lane < NT) atomicAdd(&tm_counts[b * NT + lane], mycnt);
}

// -------------------------------------------------------------------------
// accd: [2][BATCH][MPAD][32] fp32 (dot_pm, dot_sig); accs: [2][BATCH][MPAD] (ssp, ssg)
__global__ __launch_bounds__(256) void mfma_kernel(const float* __restrict__ pmask,
                                                   const uint32_t* __restrict__ packed,
                                                   float* __restrict__ accd,
                                                   float* __restrict__ accs) {
    const int kblk = blockIdx.x;
    const int mt   = blockIdx.y;
    const int b    = blockIdx.z;
    const int tid  = threadIdx.x;
    const int wv   = tid >> 6, lane = tid & 63;
    const int m0   = mt * 16;
    const int q    = lane >> 4;    // 0..3
    const int r    = lane & 15;    // 0..15
    const int kq   = r * 4;        // A-tile col base for loads

    // per-wave LDS tiles; rows padded to 72 (144B, bank-conflict-free b128)
    __shared__ __align__(16) unsigned short Apm[4][16][72];
    __shared__ __align__(16) unsigned short Asg[4][16][72];
    __shared__ __align__(16) unsigned short Bt[4][32][72];
    __shared__ float Cred[8][16][32];

    const float* pmb = pmask + (size_t)b * NQ * HWP;
    const uint32_t* pkb = packed + (size_t)b * HWP;
    const int kbase0 = kblk * KC + wv * KW;

    f32x4 Cpm0 = {0,0,0,0}, Cpm1 = {0,0,0,0}, Csg0 = {0,0,0,0}, Csg1 = {0,0,0,0};
    float rsp[4] = {0,0,0,0}, rsg[4] = {0,0,0,0};

    for (int ki = 0; ki < NITER; ++ki) {
        const int kb = kbase0 + ki * 64;
        float4 vv[4];
#pragma unroll
        for (int L = 0; L < 4; ++L) {            // load 16x64 fp32 A-tile
            int m = m0 + L * 4 + q; if (m > NQ - 1) m = NQ - 1;   // clamp pad rows
            vv[L] = *(const float4*)(pmb + (size_t)m * HWP + kb + kq);
        }
        const uint32_t wbits = pkb[kb + lane];
#pragma unroll
        for (int L = 0; L < 4; ++L) {
            const int row = L * 4 + q;
            unsigned short hp[4], hs[4];
#pragma unroll
            for (int e = 0; e < 4; ++e) {
                float pv = (&vv[L].x)[e];
                float ax = fabsf(pv);
                float en = __expf(-ax);
                float inv = __builtin_amdgcn_rcpf(1.0f + en);
                float sig = (pv >= 0.f) ? inv : en * inv;
                float sp  = fmaxf(pv, 0.f) + __logf(1.0f + en);
                rsp[L] += sp; rsg[L] += sig;
                hp[e] = f2bf(pv); hs[e] = f2bf(sig);
            }
            *(uint2*)&Apm[wv][row][kq] = make_uint2(hp[0] | ((uint32_t)hp[1] << 16),
                                                    hp[2] | ((uint32_t)hp[3] << 16));
            *(uint2*)&Asg[wv][row][kq] = make_uint2(hs[0] | ((uint32_t)hs[1] << 16),
                                                    hs[2] | ((uint32_t)hs[3] << 16));
        }
#pragma unroll
        for (int n = 0; n < NT; ++n)            // B^T unpack: lane owns pixel kb+lane
            Bt[wv][n][lane] = ((wbits >> n) & 1u) ? (unsigned short)0x3F80 : (unsigned short)0;
        // wave-local LDS ordering: drain writes before frag reads (no cross-wave
        // sharing, so no __syncthreads needed in the k-loop).
        asm volatile("s_waitcnt lgkmcnt(0)" ::: "memory");
        const short8 a0  = *(const short8*)&Apm[wv][r][q * 8];
        const short8 a1  = *(const short8*)&Apm[wv][r][32 + q * 8];
        const short8 g0  = *(const short8*)&Asg[wv][r][q * 8];
        const short8 g1  = *(const short8*)&Asg[wv][r][32 + q * 8];
        const short8 b00 = *(const short8*)&Bt[wv][r][q * 8];
        const short8 b01 = *(const short8*)&Bt[wv][r][32 + q * 8];
        const short8 b10 = *(const short8*)&Bt[wv][16 + r][q * 8];
        const short8 b11 = *(const short8*)&Bt[wv][16 + r][32 + q * 8];
        Cpm0 = __builtin_amdgcn_mfma_f32_16x16x32_bf16(a0, b00, Cpm0, 0, 0, 0);
        Cpm0 = __builtin_amdgcn_mfma_f32_16x16x32_bf16(a1, b01, Cpm0, 0, 0, 0);
        Cpm1 = __builtin_amdgcn_mfma_f32_16x16x32_bf16(a0, b10, Cpm1, 0, 0, 0);
        Cpm1 = __builtin_amdgcn_mfma_f32_16x16x32_bf16(a1, b11, Cpm1, 0, 0, 0);
        Csg0 = __builtin_amdgcn_mfma_f32_16x16x32_bf16(g0, b00, Csg0, 0, 0, 0);
        Csg0 = __builtin_amdgcn_mfma_f32_16x16x32_bf16(g1, b01, Csg0, 0, 0, 0);
        Csg1 = __builtin_amdgcn_mfma_f32_16x16x32_bf16(g0, b10, Csg1, 0, 0, 0);
        Csg1 = __builtin_amdgcn_mfma_f32_16x16x32_bf16(g1, b11, Csg1, 0, 0, 0);
        asm volatile("" ::: "memory");   // keep next iter's LDS writes below the reads
    }

    // stash C frags: C/D layout col=lane&15, row=(lane>>4)*4+reg
#pragma unroll
    for (int e = 0; e < 4; ++e) {
        const int m = q * 4 + e;
        Cred[wv * 2 + 0][m][r]      = Cpm0[e];
        Cred[wv * 2 + 0][m][16 + r] = Cpm1[e];
        Cred[wv * 2 + 1][m][r]      = Csg0[e];
        Cred[wv * 2 + 1][m][16 + r] = Csg1[e];
    }
    // row-sum reduce across the 16 lanes sharing q (contiguous 16-lane groups)
#pragma unroll
    for (int L = 0; L < 4; ++L) {
#pragma unroll
        for (int s = 8; s > 0; s >>= 1) {
            rsp[L] += __shfl_down(rsp[L], s, 16);
            rsg[L] += __shfl_down(rsg[L], s, 16);
        }
    }
    if (r == 0) {
#pragma unroll
        for (int L = 0; L < 4; ++L) {
            const int m = m0 + L * 4 + q;
            if (m < NQ) {
                atomicAdd(&accs[(size_t)b * MPAD + m], rsp[L]);
                atomicAdd(&accs[(size_t)(BATCH + b) * MPAD + m], rsg[L]);
            }
        }
    }
    __syncthreads();
    for (int idx = tid; idx < 1024; idx += 256) {
        const int type = idx >> 9, rem = idx & 511, m = rem >> 5, n = rem & 31;
        float s = Cred[0 + type][m][n] + Cred[2 + type][m][n]
                + Cred[4 + type][m][n] + Cred[6 + type][m][n];
        const int gm = m0 + m;
        if (gm < NQ)
            atomicAdd(&accd[(size_t)(type * BATCH + b) * MPAD * 32 + (size_t)gm * 32 + n], s);
    }
}

// -------------------------------------------------------------------------
// Finalize cost matrix + exact single-wave JV Hungarian (round-2 core).
__global__ __launch_bounds__(64) void hungarian_kernel(const float* __restrict__ logits,
                                                       const int* __restrict__ labels,
                                                       const float* __restrict__ accd,
                                                       const float* __restrict__ accs,
                                                       const int* __restrict__ tm_counts,
                                                       int* __restrict__ out) {
    const int b = blockIdx.x;
    const int lane = threadIdx.x;

    __shared__ double Ct[NT][NQ];
    __shared__ double u[NT + 1];
    __shared__ float smx[NQ], ssm[NQ];
    __shared__ float tcs[NT];
    __shared__ int lab[NT];

    if (lane < NT) { tcs[lane] = (float)tm_counts[b * NT + lane]; lab[lane] = labels[b * NT + lane]; }
    for (int n = lane; n < NQ; n += 64) {
        const float* lg = logits + (size_t)(b * NQ + n) * NCLS;
        float mx = -1e30f;
        for (int c = 0; c < NCLS; ++c) mx = fmaxf(mx, lg[c]);
        float s = 0.f;
        for (int c = 0; c < NCLS; ++c) s += __expf(lg[c] - mx);
        smx[n] = mx; ssm[n] = s;
    }
    if (lane <= NT) u[lane] = 0.0;
    __syncthreads();
    for (int idx = lane; idx < NQ * NT; idx += 64) {
        const int t2 = idx & 31, q2 = idx >> 5;
        float dpm = accd[(size_t)b * MPAD * 32 + q2 * 32 + t2];
        float dsg = accd[(size_t)(BATCH + b) * MPAD * 32 + q2 * 32 + t2];
        float ssp = accs[(size_t)b * MPAD + q2];
        float ssg = accs[(size_t)(BATCH + b) * MPAD + q2];
        float lg = logits[(size_t)(b * NQ + q2) * NCLS + lab[t2]];
        float prob = __expf(lg - smx[q2]) / ssm[q2];
        float c = -prob + (ssp - dpm) * (1.0f / (float)HWP)
                + 1.0f - (2.0f * dsg + 1.0f) / (ssg + tcs[t2] + 1.0f);
        if (isnan(c)) c = (float)BIGV;
        else if (isinf(c)) c = (c > 0.f) ? (float)BIGV : -(float)BIGV;
        Ct[t2][q2] = (double)c;
    }
    __syncthreads();

    const int c0 = lane + 1;
    const bool valid1 = (lane < NQ - 64);
    const int c1 = lane + 65;
    const int cidx1 = valid1 ? (lane + 64) : 0;

    double v0 = 0.0, v1 = 0.0;
    int p0 = 0, p1 = 0;

    for (int i = 1; i <= NT; ++i) {
        double minv0 = 1e300, minv1 = 1e300;
        int way0 = 0, way1 = 0;
        bool used0 = false, used1 = !valid1;
        double du0 = 0.0, du1 = 0.0, dtot = 0.0;
        int j0 = 0, i0 = i;
        int jfin = 0;

        for (int guard = 0; guard < 160; ++guard) {
            double u_i0 = u[i0];
            double cur0 = Ct[i0 - 1][lane] - u_i0 - v0;
            if (!used0 && cur0 < minv0) { minv0 = cur0; way0 = j0; }
            double cur1 = Ct[i0 - 1][cidx1] - u_i0 - v1;
            if (!used1 && cur1 < minv1) { minv1 = cur1; way1 = j0; }
            double bv = 1e301; int bj = 1 << 20;
            if (!used0) { bv = minv0; bj = c0; }
            if (!used1 && minv1 < bv) { bv = minv1; bj = c1; }
#pragma unroll
            for (int s = 32; s > 0; s >>= 1) {
                double ov = __shfl_down(bv, s, 64);
                int    oj = __shfl_down(bj, s, 64);
                if (ov < bv || (ov == bv && oj < bj)) { bv = ov; bj = oj; }
            }
            double delta = __shfl(bv, 0, 64);
            int j1 = __shfl(bj, 0, 64);
            dtot += delta;
            if (used0) { v0 -= delta; du0 += delta; } else { minv0 -= delta; }
            if (valid1) {
                if (used1) { v1 -= delta; du1 += delta; } else { minv1 -= delta; }
            }
            if (c0 == j1) used0 = true;
            if (valid1 && c1 == j1) used1 = true;
            int src = (j1 - 1) & 63, slot = (j1 - 1) >> 6;
            int pa = __shfl(p0, src, 64), pb = __shfl(p1, src, 64);
            int pj1 = slot ? pb : pa;
            if (pj1 == 0) { jfin = j1; break; }
            j0 = j1; i0 = pj1;
        }

        if (used0 && p0 != 0) u[p0] += du0;
        if (valid1 && used1 && p1 != 0) u[p1] += du1;
        if (lane == 0) u[i] += dtot;

        int jj = jfin;
        for (int guard = 0; guard < 160 && jj != 0; ++guard) {
            int src = (jj - 1) & 63, slot = (jj - 1) >> 6;
            int wa = __shfl(way0, src, 64), wb = __shfl(way1, src, 64);
            int jprev = slot ? wb : wa;
            int pnew;
            if (jprev == 0) pnew = i;
            else {
                int s2 = (jprev - 1) & 63, sl2 = (jprev - 1) >> 6;
                int pa = __shfl(p0, s2, 64), pb = __shfl(p1, s2, 64);
                pnew = sl2 ? pb : pa;
            }
            if (c0 == jj) p0 = pnew;
            if (valid1 && c1 == jj) p1 = pnew;
            jj = jprev;
        }
        __syncthreads();
    }

    unsigned long long m0 = __ballot(p0 != 0);
    unsigned long long m1 = __ballot(valid1 && p1 != 0);
    int base = b * NT;
    if (p0 != 0) {
        int rank = __popcll(m0 & ((1ull << lane) - 1ull));
        out[base + rank] = c0 - 1;
        out[BATCH * NT + base + rank] = p0 - 1;
    }
    if (valid1 && p1 != 0) {
        int rank = __popcll(m0) + __popcll(m1 & ((1ull << lane) - 1ull));
        out[base + rank] = c1 - 1;
        out[BATCH * NT + base + rank] = p1 - 1;
    }
}

// -------------------------------------------------------------------------
extern "C" void kernel_launch(void* const* d_in, const int* in_sizes, int n_in,
                              void* d_out, int out_size, void* d_ws, size_t ws_size,
                              hipStream_t stream) {
    const float* logits = (const float*)d_in[0];   // [8,100,81]
    const float* pmasks = (const float*)d_in[1];   // [8,100,256,256]
    const float* tmasks = (const float*)d_in[2];   // [8,32,512,512]
    const int*   labels = (const int*)d_in[3];     // [8,32]

    uint8_t* ws = (uint8_t*)d_ws;
    uint32_t* packed = (uint32_t*)ws;                       // 2 MiB
    uint8_t* zbase = ws + (size_t)BATCH * HWP * 4;
    int* tm_counts = (int*)zbase;                           // 1 KiB
    float* accd = (float*)(zbase + 1024);                   // 2*8*112*32*4 = 229376 B
    float* accs = (float*)(zbase + 1024 + 229376);          // 2*8*112*4 = 7168 B
    const size_t ztotal = 1024 + 229376 + 7168;

    int* out = (int*)d_out;   // int32: src [8,32] then tgt [8,32]

    hipMemsetAsync(zbase, 0, ztotal, stream);
    pack_kernel<<<BATCH * HWP / 256, 256, 0, stream>>>(tmasks, packed, tm_counts);
    mfma_kernel<<<dim3(KSPLIT, MTILES, BATCH), 256, 0, stream>>>(pmasks, packed, accd, accs);
    hungarian_kernel<<<BATCH, 64, 0, stream>>>(logits, labels, accd, accs, tm_counts, out);
}

// Round 4
// 598.553 us; speedup vs baseline: 1.6033x; 1.0123x over previous
//
#include <hip/hip_runtime.h>
#include <stdint.h>

// HungarianMatcher on MI355X — round 4: LDS-free MFMA k-loop.
// Round 3's k-loop had two full-fence LDS round trips per iteration (staging
// A and B tiles), blocking software pipelining. This round each lane loads its
// MFMA fragments DIRECTLY from global in fragment order:
//   A[m=lane&15][k=(lane>>4)*8+j]  -> 4x float4 per frag-pair, coalesced
//   B bits from packed[] as 4x uint4 (16 lanes share addrs -> L1 broadcast)
// fp32 -> sigmoid/softplus -> bf16 conversion happens in registers; no LDS,
// no fences in the loop, compiler free to pipeline with fine-grained vmcnt.
// Hungarian: u[] mirrored in lane registers (shfl ~40cyc vs LDS ~120cyc on
// the serial Dijkstra critical path).

#define BATCH 8
#define NQ    100
#define NT    32
#define HWP   65536      // 256*256
#define NCLS  81
#define BIGV  1.0e6
#define MPAD  112        // 7*16
#define MTILES 7
#define KSPLIT 16
#define KC (HWP / KSPLIT)   // 4096 px per block
#define KW (KC / 4)         // 1024 px per wave
#define NITER (KW / 64)     // 16 k-iters of 64 px

typedef __attribute__((ext_vector_type(8))) short short8;
typedef __attribute__((ext_vector_type(4))) float f32x4;

__device__ inline unsigned short f2bf(float f) {   // RNE fp32->bf16
    uint32_t u = __builtin_bit_cast(uint32_t, f);
    u += 0x7fffu + ((u >> 16) & 1u);
    return (unsigned short)(u >> 16);
}

// -------------------------------------------------------------------------
__global__ __launch_bounds__(256) void pack_kernel(const float* __restrict__ tmask,
                                                   uint32_t* __restrict__ packed,
                                                   int* __restrict__ tm_counts) {
    int idx = blockIdx.x * 256 + threadIdx.x;
    int b = idx >> 16;
    int p = idx & 65535;
    int y = p >> 8, x = p & 255;
    const float* base = tmask + (size_t)b * NT * 262144 + (size_t)(2 * y) * 512 + (2 * x);
    uint32_t w = 0;
#pragma unroll
    for (int t = 0; t < NT; ++t) {
        float v = base[(size_t)t * 262144];
        w |= (v > 0.5f ? 1u : 0u) << t;
    }
    packed[idx] = w;
    int lane = threadIdx.x & 63;
    int mycnt = 0;
#pragma unroll
    for (int t = 0; t < NT; ++t) {
        unsigned long long m = __ballot((w >> t) & 1u);
        if (lane == t) mycnt = __popcll(m);
    }
    if (lane < NT) atomicAdd(&tm_counts[b * NT + lane], mycnt);
}

// -------------------------------------------------------------------------
// accd: [2][BATCH][MPAD][32] fp32 (dot_pm, dot_sig); accs: [2][BATCH][MPAD]
__global__ __launch_bounds__(256) void mfma_kernel(const float* __restrict__ pmask,
                                                   const uint32_t* __restrict__ packed,
                                                   float* __restrict__ accd,
                                                   float* __restrict__ accs) {
    const int kblk = blockIdx.x;
    const int mt   = blockIdx.y;
    const int b    = blockIdx.z;
    const int tid  = threadIdx.x;
    const int wv   = tid >> 6, lane = tid & 63;
    const int m0   = mt * 16;
    const int q    = lane >> 4;    // 0..3  (k-quad)
    const int r    = lane & 15;    // 0..15 (A row / B target)

    __shared__ float Cred[8][16][32];

    int mrow = m0 + r; if (mrow > NQ - 1) mrow = NQ - 1;   // pad rows duplicate row 99
    const float* Arow = pmask + (size_t)b * NQ * HWP + (size_t)mrow * HWP;
    const uint32_t* pkb = packed + (size_t)b * HWP;
    const int kbase0 = kblk * KC + wv * KW;

    f32x4 Cpm0 = {0,0,0,0}, Cpm1 = {0,0,0,0}, Csg0 = {0,0,0,0}, Csg1 = {0,0,0,0};
    float rsp = 0.f, rsg = 0.f;

    for (int ki = 0; ki < NITER; ++ki) {
        const int kb = kbase0 + ki * 64;
        // --- direct fragment loads (no LDS) ---
        const float4 va0 = *(const float4*)(Arow + kb + q * 8);
        const float4 va1 = *(const float4*)(Arow + kb + q * 8 + 4);
        const float4 va2 = *(const float4*)(Arow + kb + 32 + q * 8);
        const float4 va3 = *(const float4*)(Arow + kb + 32 + q * 8 + 4);
        const uint4  wb0 = *(const uint4*)(pkb + kb + q * 8);
        const uint4  wb1 = *(const uint4*)(pkb + kb + q * 8 + 4);
        const uint4  wb2 = *(const uint4*)(pkb + kb + 32 + q * 8);
        const uint4  wb3 = *(const uint4*)(pkb + kb + 32 + q * 8 + 4);

        short8 a0, a1, g0, g1;
        auto cvt4 = [&](const float4& v, short8& af, short8& gf, int base) {
#pragma unroll
            for (int e = 0; e < 4; ++e) {
                float pv = (&v.x)[e];
                float ax = fabsf(pv);
                float en = __expf(-ax);
                float inv = __builtin_amdgcn_rcpf(1.0f + en);
                float sig = (pv >= 0.f) ? inv : en * inv;
                float sp  = fmaxf(pv, 0.f) + __logf(1.0f + en);
                rsp += sp; rsg += sig;
                af[base + e] = (short)f2bf(pv);
                gf[base + e] = (short)f2bf(sig);
            }
        };
        cvt4(va0, a0, g0, 0); cvt4(va1, a0, g0, 4);
        cvt4(va2, a1, g1, 0); cvt4(va3, a1, g1, 4);

        short8 b00, b01, b10, b11;
        const unsigned short ONE = 0x3F80;
#pragma unroll
        for (int j = 0; j < 4; ++j) {
            uint32_t s;
            s = (&wb0.x)[j] >> r;
            b00[j]     = (short)((s & 1u)         ? ONE : 0);
            b10[j]     = (short)(((s >> 16) & 1u) ? ONE : 0);
            s = (&wb1.x)[j] >> r;
            b00[4 + j] = (short)((s & 1u)         ? ONE : 0);
            b10[4 + j] = (short)(((s >> 16) & 1u) ? ONE : 0);
            s = (&wb2.x)[j] >> r;
            b01[j]     = (short)((s & 1u)         ? ONE : 0);
            b11[j]     = (short)(((s >> 16) & 1u) ? ONE : 0);
            s = (&wb3.x)[j] >> r;
            b01[4 + j] = (short)((s & 1u)         ? ONE : 0);
            b11[4 + j] = (short)(((s >> 16) & 1u) ? ONE : 0);
        }

        Cpm0 = __builtin_amdgcn_mfma_f32_16x16x32_bf16(a0, b00, Cpm0, 0, 0, 0);
        Cpm0 = __builtin_amdgcn_mfma_f32_16x16x32_bf16(a1, b01, Cpm0, 0, 0, 0);
        Cpm1 = __builtin_amdgcn_mfma_f32_16x16x32_bf16(a0, b10, Cpm1, 0, 0, 0);
        Cpm1 = __builtin_amdgcn_mfma_f32_16x16x32_bf16(a1, b11, Cpm1, 0, 0, 0);
        Csg0 = __builtin_amdgcn_mfma_f32_16x16x32_bf16(g0, b00, Csg0, 0, 0, 0);
        Csg0 = __builtin_amdgcn_mfma_f32_16x16x32_bf16(g1, b01, Csg0, 0, 0, 0);
        Csg1 = __builtin_amdgcn_mfma_f32_16x16x32_bf16(g0, b10, Csg1, 0, 0, 0);
        Csg1 = __builtin_amdgcn_mfma_f32_16x16x32_bf16(g1, b11, Csg1, 0, 0, 0);
    }

    // row sums: reduce across the 4 k-quads (lane bits 4,5) -> q==0 lanes
    rsp += __shfl_xor(rsp, 16, 64);
    rsp += __shfl_xor(rsp, 32, 64);
    rsg += __shfl_xor(rsg, 16, 64);
    rsg += __shfl_xor(rsg, 32, 64);
    if (q == 0 && m0 + r < NQ) {
        atomicAdd(&accs[(size_t)b * MPAD + m0 + r], rsp);
        atomicAdd(&accs[(size_t)(BATCH + b) * MPAD + m0 + r], rsg);
    }

    // C/D layout: col = lane&15 (target), row = (lane>>4)*4 + e (query)
#pragma unroll
    for (int e = 0; e < 4; ++e) {
        const int m = q * 4 + e;
        Cred[wv * 2 + 0][m][r]      = Cpm0[e];
        Cred[wv * 2 + 0][m][16 + r] = Cpm1[e];
        Cred[wv * 2 + 1][m][r]      = Csg0[e];
        Cred[wv * 2 + 1][m][16 + r] = Csg1[e];
    }
    __syncthreads();
    for (int idx = tid; idx < 1024; idx += 256) {
        const int type = idx >> 9, rem = idx & 511, m = rem >> 5, n = rem & 31;
        float s = Cred[0 + type][m][n] + Cred[2 + type][m][n]
                + Cred[4 + type][m][n] + Cred[6 + type][m][n];
        const int gm = m0 + m;
        if (gm < NQ)
            atomicAdd(&accd[(size_t)(type * BATCH + b) * MPAD * 32 + (size_t)gm * 32 + n], s);
    }
}

// -------------------------------------------------------------------------
// Finalize cost matrix + exact single-wave JV Hungarian.
__global__ __launch_bounds__(64) void hungarian_kernel(const float* __restrict__ logits,
                                                       const int* __restrict__ labels,
                                                       const float* __restrict__ accd,
                                                       const float* __restrict__ accs,
                                                       const int* __restrict__ tm_counts,
                                                       int* __restrict__ out) {
    const int b = blockIdx.x;
    const int lane = threadIdx.x;

    __shared__ double Ct[NT][NQ];
    __shared__ double u[NT + 1];
    __shared__ float smx[NQ], ssm[NQ];
    __shared__ float tcs[NT];
    __shared__ int lab[NT];

    if (lane < NT) { tcs[lane] = (float)tm_counts[b * NT + lane]; lab[lane] = labels[b * NT + lane]; }
    for (int n = lane; n < NQ; n += 64) {
        const float* lg = logits + (size_t)(b * NQ + n) * NCLS;
        float mx = -1e30f;
        for (int c = 0; c < NCLS; ++c) mx = fmaxf(mx, lg[c]);
        float s = 0.f;
        for (int c = 0; c < NCLS; ++c) s += __expf(lg[c] - mx);
        smx[n] = mx; ssm[n] = s;
    }
    if (lane <= NT) u[lane] = 0.0;
    __syncthreads();
    for (int idx = lane; idx < NQ * NT; idx += 64) {
        const int t2 = idx & 31, q2 = idx >> 5;
        float dpm = accd[(size_t)b * MPAD * 32 + q2 * 32 + t2];
        float dsg = accd[(size_t)(BATCH + b) * MPAD * 32 + q2 * 32 + t2];
        float ssp = accs[(size_t)b * MPAD + q2];
        float ssg = accs[(size_t)(BATCH + b) * MPAD + q2];
        float lg = logits[(size_t)(b * NQ + q2) * NCLS + lab[t2]];
        float prob = __expf(lg - smx[q2]) / ssm[q2];
        float c = -prob + (ssp - dpm) * (1.0f / (float)HWP)
                + 1.0f - (2.0f * dsg + 1.0f) / (ssg + tcs[t2] + 1.0f);
        if (isnan(c)) c = (float)BIGV;
        else if (isinf(c)) c = (c > 0.f) ? (float)BIGV : -(float)BIGV;
        Ct[t2][q2] = (double)c;
    }
    __syncthreads();

    const int c0 = lane + 1;
    const bool valid1 = (lane < NQ - 64);
    const int c1 = lane + 65;
    const int cidx1 = valid1 ? (lane + 64) : 0;

    double v0 = 0.0, v1 = 0.0;
    int p0 = 0, p1 = 0;
    double u_reg = 0.0;                       // mirror of u[lane] (lanes 0..32)

    for (int i = 1; i <= NT; ++i) {
        double minv0 = 1e300, minv1 = 1e300;
        int way0 = 0, way1 = 0;
        bool used0 = false, used1 = !valid1;
        double du0 = 0.0, du1 = 0.0, dtot = 0.0;
        int j0 = 0, i0 = i;
        int jfin = 0;

        for (int guard = 0; guard < 160; ++guard) {
            double u_i0 = __shfl(u_reg, i0, 64);     // reg-mirror broadcast
            double cur0 = Ct[i0 - 1][lane] - u_i0 - v0;
            if (!used0 && cur0 < minv0) { minv0 = cur0; way0 = j0; }
            double cur1 = Ct[i0 - 1][cidx1] - u_i0 - v1;
            if (!used1 && cur1 < minv1) { minv1 = cur1; way1 = j0; }
            double bv = 1e301; int bj = 1 << 20;
            if (!used0) { bv = minv0; bj = c0; }
            if (!used1 && minv1 < bv) { bv = minv1; bj = c1; }
#pragma unroll
            for (int s = 32; s > 0; s >>= 1) {
                double ov = __shfl_down(bv, s, 64);
                int    oj = __shfl_down(bj, s, 64);
                if (ov < bv || (ov == bv && oj < bj)) { bv = ov; bj = oj; }
            }
            double delta = __shfl(bv, 0, 64);
            int j1 = __shfl(bj, 0, 64);
            dtot += delta;
            if (used0) { v0 -= delta; du0 += delta; } else { minv0 -= delta; }
            if (valid1) {
                if (used1) { v1 -= delta; du1 += delta; } else { minv1 -= delta; }
            }
            if (c0 == j1) used0 = true;
            if (valid1 && c1 == j1) used1 = true;
            int src = (j1 - 1) & 63, slot = (j1 - 1) >> 6;
            int pa = __shfl(p0, src, 64), pb = __shfl(p1, src, 64);
            int pj1 = slot ? pb : pa;
            if (pj1 == 0) { jfin = j1; break; }
            j0 = j1; i0 = pj1;
        }

        // deferred u updates (distinct rows across used cols -> race-free)
        if (used0 && p0 != 0) u[p0] += du0;
        if (valid1 && used1 && p1 != 0) u[p1] += du1;
        if (lane == 0) u[i] += dtot;

        int jj = jfin;
        for (int guard = 0; guard < 160 && jj != 0; ++guard) {
            int src = (jj - 1) & 63, slot = (jj - 1) >> 6;
            int wa = __shfl(way0, src, 64), wb = __shfl(way1, src, 64);
            int jprev = slot ? wb : wa;
            int pnew;
            if (jprev == 0) pnew = i;
            else {
                int s2 = (jprev - 1) & 63, sl2 = (jprev - 1) >> 6;
                int pa = __shfl(p0, s2, 64), pb = __shfl(p1, s2, 64);
                pnew = sl2 ? pb : pa;
            }
            if (c0 == jj) p0 = pnew;
            if (valid1 && c1 == jj) p1 = pnew;
            jj = jprev;
        }
        __syncthreads();
        u_reg = (lane <= NT) ? u[lane] : 0.0;   // refresh mirror once per row
    }

    unsigned long long m0 = __ballot(p0 != 0);
    unsigned long long m1 = __ballot(valid1 && p1 != 0);
    int base = b * NT;
    if (p0 != 0) {
        int rank = __popcll(m0 & ((1ull << lane) - 1ull));
        out[base + rank] = c0 - 1;
        out[BATCH * NT + base + rank] = p0 - 1;
    }
    if (valid1 && p1 != 0) {
        int rank = __popcll(m0) + __popcll(m1 & ((1ull << lane) - 1ull));
        out[base + rank] = c1 - 1;
        out[BATCH * NT + base + rank] = p1 - 1;
    }
}

// -------------------------------------------------------------------------
extern "C" void kernel_launch(void* const* d_in, const int* in_sizes, int n_in,
                              void* d_out, int out_size, void* d_ws, size_t ws_size,
                              hipStream_t stream) {
    const float* logits = (const float*)d_in[0];   // [8,100,81]
    const float* pmasks = (const float*)d_in[1];   // [8,100,256,256]
    const float* tmasks = (const float*)d_in[2];   // [8,32,512,512]
    const int*   labels = (const int*)d_in[3];     // [8,32]

    uint8_t* ws = (uint8_t*)d_ws;
    uint32_t* packed = (uint32_t*)ws;                       // 2 MiB
    uint8_t* zbase = ws + (size_t)BATCH * HWP * 4;
    int* tm_counts = (int*)zbase;                           // 1 KiB
    float* accd = (float*)(zbase + 1024);                   // 229376 B
    float* accs = (float*)(zbase + 1024 + 229376);          // 7168 B
    const size_t ztotal = 1024 + 229376 + 7168;

    int* out = (int*)d_out;   // int32: src [8,32] then tgt [8,32]

    hipMemsetAsync(zbase, 0, ztotal, stream);
    pack_kernel<<<BATCH * HWP / 256, 256, 0, stream>>>(tmasks, packed, tm_counts);
    mfma_kernel<<<dim3(KSPLIT, MTILES, BATCH), 256, 0, stream>>>(pmasks, packed, accd, accs);
    hungarian_kernel<<<BATCH, 64, 0, stream>>>(logits, labels, accd, accs, tm_counts, out);
}